// Round 6
// baseline (218.471 us; speedup 1.0000x reference)
//
#include <hip/hip_runtime.h>
#include <hip/hip_bf16.h>
#include <math.h>

typedef __bf16 bf16;
typedef __bf16 bf16x8 __attribute__((ext_vector_type(8)));
typedef float f32x4 __attribute__((ext_vector_type(4)));

#define SEQ 2048
#define EMB 1024
#define NH  16
#define HD  64

// async global->LDS, 16B per lane (wave-uniform LDS base + lane*16)
#define GLOAD_LDS16(gp, lp)                                             \
    __builtin_amdgcn_global_load_lds(                                   \
        (const __attribute__((address_space(1))) void*)(gp),            \
        (__attribute__((address_space(3))) void*)(lp), 16, 0, 0)

// fp32x8 -> bf16x8 convert helper
__device__ __forceinline__ bf16x8 cvt8(const float4& f0, const float4& f1) {
    bf16x8 v;
    v[0] = (bf16)f0.x; v[1] = (bf16)f0.y; v[2] = (bf16)f0.z; v[3] = (bf16)f0.w;
    v[4] = (bf16)f1.x; v[5] = (bf16)f1.y; v[6] = (bf16)f1.z; v[7] = (bf16)f1.w;
    return v;
}

// ---------------------------------------------------------------------------
// Kernel 1: fused fp32 QKV projection (y = x @ W^T) + RoPE epilogue.
//  R13: cvt kernel ELIMINATED. A (x) and B (W) are read as fp32 float4 pairs,
//  converted to bf16 in-register, ds_write'd into a 2-buffer LDS pipeline:
//    { s_waitcnt vmcnt(0) [tile kt regs arrived]; ds_write buf p;
//      __syncthreads() [vmcnt already 0 -> no drain penalty];
//      issue loads kt+1 [fly under compute]; compute p }
//  RoPE cos/sin table (128 rows x 32 freqs) built cooperatively into LDS at
//  kernel start (16 fp64-range-reduced sincosf per thread), overlapping the
//  first tile's load latency. No ctab dependency, no cvt launch, no gap.
//  Q pre-scaled by 1/32, stored [B,H,S,D]. K,V stored in MFMA-fragment order
//  (layouts byte-identical to previous rounds; attn unchanged).
// ---------------------------------------------------------------------------
__global__ __launch_bounds__(256) void qkv_rope_kernel(
    const float* __restrict__ x,
    const float* __restrict__ Wq, const float* __restrict__ Wk, const float* __restrict__ Wv,
    bf16* __restrict__ q_ws, bf16* __restrict__ kf_ws, bf16* __restrict__ vf_ws)
{
    // [0,32768): 2 x (As 8KB | Bs 8KB) staging bufs; epilogue Es overlaps.
    // [36864,53248): cos table f32[128][32]; [53248,69632): sin table.
    __shared__ __align__(16) char SM[69632];
    float* tabc = (float*)(SM + 36864);
    float* tabs = (float*)(SM + 53248);

    const int t    = threadIdx.x;
    const int lane = t & 63;
    const int wave = t >> 6;
    const int col  = lane & 15;
    const int quad = lane >> 4;

    const int nblk = blockIdx.x;              // 0..23
    const int m0   = blockIdx.y * 128;

    const float* W; int nloc;
    if (nblk < 8)       { W = Wq; nloc = nblk * 128; }
    else if (nblk < 16) { W = Wk; nloc = (nblk - 8) * 128; }
    else                { W = Wv; nloc = (nblk - 16) * 128; }

    // staging slots: c = t and t+256; row = c>>2 (0..127), col8 = (c&3)*8
    const float *gA[2], *gB[2];
#pragma unroll
    for (int j = 0; j < 2; j++) {
        int c = t + j * 256;
        gA[j] = x + (size_t)(m0   + (c >> 2)) * EMB + (c & 3) * 8;
        gB[j] = W + (size_t)(nloc + (c >> 2)) * EMB + (c & 3) * 8;
    }

    const int wm = (wave >> 1) * 64;
    const int wn = (wave & 1) * 64;

    f32x4 acc[4][4];
#pragma unroll
    for (int i = 0; i < 4; i++)
#pragma unroll
        for (int j = 0; j < 4; j++) acc[i][j] = (f32x4){0.f, 0.f, 0.f, 0.f};

    float4 rA[2][2], rB[2][2];
    auto issue = [&](int kt) {
        const int kc = kt * 32;
#pragma unroll
        for (int j = 0; j < 2; j++) {
            rA[j][0] = *(const float4*)(gA[j] + kc);
            rA[j][1] = *(const float4*)(gA[j] + kc + 4);
            rB[j][0] = *(const float4*)(gB[j] + kc);
            rB[j][1] = *(const float4*)(gB[j] + kc + 4);
        }
    };
    auto write_buf = [&](int p) {
        bf16* As_ = (bf16*)(SM + p * 16384);
        bf16* Bs_ = (bf16*)(SM + p * 16384 + 8192);
#pragma unroll
        for (int j = 0; j < 2; j++) {
            int c = t + j * 256;
            *(bf16x8*)(As_ + c * 8) = cvt8(rA[j][0], rA[j][1]);
            *(bf16x8*)(Bs_ + c * 8) = cvt8(rB[j][0], rB[j][1]);
        }
    };
    auto compute = [&](int p) {
        const bf16* As_ = (const bf16*)(SM + p * 16384);
        const bf16* Bs_ = (const bf16*)(SM + p * 16384 + 8192);
        bf16x8 a[4], bb[4];
#pragma unroll
        for (int mt = 0; mt < 4; mt++)
            a[mt] = *(const bf16x8*)(As_ + (wm + mt * 16 + col) * 32 + quad * 8);
#pragma unroll
        for (int nt = 0; nt < 4; nt++)
            bb[nt] = *(const bf16x8*)(Bs_ + (wn + nt * 16 + col) * 32 + quad * 8);
#pragma unroll
        for (int mt = 0; mt < 4; mt++)
#pragma unroll
            for (int nt = 0; nt < 4; nt++)
                acc[mt][nt] = __builtin_amdgcn_mfma_f32_16x16x32_bf16(a[mt], bb[nt], acc[mt][nt], 0, 0, 0);
    };

    issue(0);                       // first tile's 8 loads in flight

    // build RoPE table while loads fly: rows (m0&2047)+0..127, 32 freqs
    {
        const int sbase = m0 & (SEQ - 1);
        const double TWOPI = 6.283185307179586476;
        const double INV2PI = 0.15915494309189533577;
#pragma unroll
        for (int i = 0; i < 16; i++) {
            int idx = t * 16 + i;               // 0..4095 = row*32 + jj
            int row = idx >> 5;
            int jj  = idx & 31;
            float freq = exp2f((float)jj * -0.4152410118609203f); // 10000^(-jj/32)
            double a = (double)(sbase + row) * (double)freq;
            double n = floor(a * INV2PI);
            float red = (float)(a - n * TWOPI);
            tabc[idx] = __cosf(red);
            tabs[idx] = __sinf(red);
        }
    }

    for (int kt = 0; kt < 32; kt++) {
        const int p = kt & 1;
        asm volatile("s_waitcnt vmcnt(0)" ::: "memory");   // tile kt regs ready
        write_buf(p);
        __syncthreads();           // lgkm drain; vmcnt already 0 -> cheap
        if (kt < 31) issue(kt + 1);
        compute(p);
    }
    __syncthreads();               // all LDS reads done -> bufs reusable as Es

    // ---- epilogue: RoPE + LDS transpose -> coalesced stores ----
    bf16* Es = (bf16*)SM + wave * 4608;          // 9216 B per wave

    const int n0w  = nblk * 128 + wn;
    const int m0w  = m0 + wm;
    const int bb_  = m0w >> 11;
    const int ss0  = m0w & (SEQ - 1);
    const int h    = (n0w >> 6) & 15;
    const int bh   = bb_ * NH + h;
    const int kind = (n0w < 1024) ? 0 : (n0w < 2048 ? 1 : 2);  // Q/K/V

#pragma unroll
    for (int mt = 0; mt < 4; mt++) {
#pragma unroll
        for (int nt = 0; nt < 4; nt++) {
            const int d  = nt * 16 + col;
            const int jj = d >> 1;
#pragma unroll
            for (int r = 0; r < 4; r++) {
                const int ss_l = mt * 16 + quad * 4 + r;
                float v = acc[mt][nt][r];
                if (kind < 2) {   // uniform per block
                    float partner = __shfl_xor(v, 1, 64);
                    const int ti = (wm + ss_l) * 32 + jj;   // block-local row
                    float c  = tabc[ti];
                    float sn = tabs[ti];
                    float o = ((d & 1) == 0) ? (v * c - partner * sn)
                                             : (partner * sn + v * c);
                    if (kind == 0) {
                        Es[ss_l * 72 + d] = (bf16)(o * 0.03125f);   // pre-scaled Q
                    } else {
                        int eoff = ((ss_l >> 4) * 2 + (d >> 5)) * 512
                                 + ((d >> 3) & 3) * 128 + (ss_l & 15) * 8 + (d & 7);
                        Es[eoff] = (bf16)o;
                    }
                } else {
                    int eoff = ((ss_l >> 5) * 4 + (d >> 4)) * 512
                             + ((ss_l >> 3) & 3) * 128 + (d & 15) * 8 + (ss_l & 7);
                    Es[eoff] = (bf16)v;
                }
            }
        }
    }
    // wave-private region: compiler inserts lgkmcnt waits.

    const int row = lane >> 3, c8 = lane & 7;
    if (kind == 0) {
        bf16* qbase = q_ws + ((size_t)bh * SEQ + ss0) * HD;
#pragma unroll
        for (int i = 0; i < 8; i++) {
            bf16x8 vv = *(const bf16x8*)&Es[(i * 8 + row) * 72 + c8 * 8];
            *(bf16x8*)(qbase + (size_t)(i * 8 + row) * HD + c8 * 8) = vv;
        }
    } else if (kind == 1) {
        bf16* kbase = kf_ws + ((size_t)bh * 128 + (ss0 >> 4)) * 1024;
#pragma unroll
        for (int i = 0; i < 8; i++) {
            bf16x8 vv = *(const bf16x8*)&Es[i * 512 + lane * 8];
            *(bf16x8*)(kbase + i * 512 + lane * 8) = vv;
        }
    } else {
        bf16* vbase = vf_ws + ((size_t)bh * 64 + (ss0 >> 5)) * 2048;
#pragma unroll
        for (int i = 0; i < 8; i++) {
            bf16x8 vv = *(const bf16x8*)&Es[i * 512 + lane * 8];
            *(bf16x8*)(vbase + i * 512 + lane * 8) = vv;
        }
    }
}

// ---------------------------------------------------------------------------
// Kernel 2: flash attention (causal). Q pre-scaled by 1/32 upstream.
//  Fixed-reference softmax (m=0): split-K partials combine by pure addition.
//  K/V read directly from global in MFMA-fragment order. s_setprio around
//  MFMA clusters (R11). Unchanged.
// ---------------------------------------------------------------------------
__global__ __launch_bounds__(128) void attn_kernel(
    const bf16* __restrict__ q_ws, const bf16* __restrict__ kf,
    const bf16* __restrict__ vf, bf16* __restrict__ attn_ws)
{
    __shared__ float comb_o[2][4][4][64];   // [frag][nt][r][lane] from wave1
    __shared__ float comb_l[2][64];

    const int lane = threadIdx.x & 63;
    const int wave = threadIdx.x >> 6;
    const int col  = lane & 15;
    const int quad = lane >> 4;

    const int qt = 63 - (int)(blockIdx.x >> 5);  // longest first, 64 q-tiles of 32
    const int bh = blockIdx.x & 31;              // b*16+h
    const int b_ = bh >> 4;
    const int h  = bh & 15;
    const int qb = qt * 32;
    const int nk = qt + 1;                       // 32-key tiles incl. diagonal

    const bf16* Q  = q_ws + (size_t)bh * SEQ * HD;
    const bf16* Kf = kf + (size_t)bh * 131072;
    const bf16* Vf = vf + (size_t)bh * 131072;

    bf16x8 aq[2][2];
#pragma unroll
    for (int f = 0; f < 2; f++) {
        const bf16* qp = Q + (size_t)(qb + f * 16 + col) * HD + quad * 8;
        aq[f][0] = *(const bf16x8*)(qp);
        aq[f][1] = *(const bf16x8*)(qp + 32);
    }

    f32x4 acc_o[2][4];
#pragma unroll
    for (int f = 0; f < 2; f++)
#pragma unroll
        for (int i = 0; i < 4; i++) acc_o[f][i] = (f32x4){0.f, 0.f, 0.f, 0.f};
    float lsum[2] = {0.f, 0.f};

    int psrc[8];
#pragma unroll
    for (int j = 0; j < 8; j++)
        psrc[j] = ((((quad * 2 + (j >> 2)) & 3) << 4) | col) << 2;

    int s0 = (wave < nk) ? wave : 0;
    bf16x8 Ka[2][2], nKa[2][2];
    {
        const bf16* p = Kf + (size_t)s0 * 2048 + lane * 8;
        Ka[0][0] = *(const bf16x8*)(p);
        Ka[0][1] = *(const bf16x8*)(p + 512);
        Ka[1][0] = *(const bf16x8*)(p + 1024);
        Ka[1][1] = *(const bf16x8*)(p + 1536);
    }

    for (int s = wave; s < nk; s += 2) {
        bf16x8 Vb[4];
        {
            const bf16* p = Vf + (size_t)s * 2048 + lane * 8;
            Vb[0] = *(const bf16x8*)(p);
            Vb[1] = *(const bf16x8*)(p + 512);
            Vb[2] = *(const bf16x8*)(p + 1024);
            Vb[3] = *(const bf16x8*)(p + 1536);
        }

        f32x4 sT[2][2];
        __builtin_amdgcn_s_setprio(1);
#pragma unroll
        for (int g = 0; g < 2; g++)
#pragma unroll
            for (int f = 0; f < 2; f++) {
                f32x4 z = (f32x4){0.f, 0.f, 0.f, 0.f};
                z = __builtin_amdgcn_mfma_f32_16x16x32_bf16(Ka[g][0], aq[f][0], z, 0, 0, 0);
                z = __builtin_amdgcn_mfma_f32_16x16x32_bf16(Ka[g][1], aq[f][1], z, 0, 0, 0);
                sT[g][f] = z;
            }
        __builtin_amdgcn_s_setprio(0);

        {
            int sn = (s + 2 < nk) ? s + 2 : s;
            const bf16* p = Kf + (size_t)sn * 2048 + lane * 8;
            nKa[0][0] = *(const bf16x8*)(p);
            nKa[0][1] = *(const bf16x8*)(p + 512);
            nKa[1][0] = *(const bf16x8*)(p + 1024);
            nKa[1][1] = *(const bf16x8*)(p + 1536);
        }

        float p[2][2][4];
        if (s == nk - 1) {
#pragma unroll
            for (int g = 0; g < 2; g++)
#pragma unroll
                for (int f = 0; f < 2; f++) {
                    const int qg = qb + f * 16 + col;
#pragma unroll
                    for (int r = 0; r < 4; r++) {
                        int key = s * 32 + g * 16 + quad * 4 + r;
                        float e = (key <= qg) ? __expf(sT[g][f][r]) : 0.f;
                        p[g][f][r] = e;
                        lsum[f] += e;
                    }
                }
        } else {
#pragma unroll
            for (int g = 0; g < 2; g++)
#pragma unroll
                for (int f = 0; f < 2; f++)
#pragma unroll
                    for (int r = 0; r < 4; r++) {
                        float e = __expf(sT[g][f][r]);
                        p[g][f][r] = e;
                        lsum[f] += e;
                    }
        }

#pragma unroll
        for (int f = 0; f < 2; f++) {
            unsigned int pk[4];
#pragma unroll
            for (int r = 0; r < 4; r++) {
                unsigned int lo = __builtin_bit_cast(unsigned short, (bf16)p[0][f][r]);
                unsigned int hi = __builtin_bit_cast(unsigned short, (bf16)p[1][f][r]);
                pk[r] = (hi << 16) | lo;
            }
            bf16x8 a_p;
#pragma unroll
            for (int j = 0; j < 8; j++) {
                unsigned int g = (unsigned int)__builtin_amdgcn_ds_bpermute(psrc[j], (int)pk[j & 3]);
                unsigned short bits = (quad < 2) ? (unsigned short)(g & 0xffff)
                                                 : (unsigned short)(g >> 16);
                a_p[j] = __builtin_bit_cast(bf16, bits);
            }
            __builtin_amdgcn_s_setprio(1);
#pragma unroll
            for (int nt = 0; nt < 4; nt++)
                acc_o[f][nt] = __builtin_amdgcn_mfma_f32_16x16x32_bf16(a_p, Vb[nt], acc_o[f][nt], 0, 0, 0);
            __builtin_amdgcn_s_setprio(0);
        }

        Ka[0][0] = nKa[0][0]; Ka[0][1] = nKa[0][1];
        Ka[1][0] = nKa[1][0]; Ka[1][1] = nKa[1][1];
    }

    if (wave == 1) {
#pragma unroll
        for (int f = 0; f < 2; f++) {
            comb_l[f][lane] = lsum[f];
#pragma unroll
            for (int nt = 0; nt < 4; nt++)
#pragma unroll
                for (int r = 0; r < 4; r++)
                    comb_o[f][nt][r][lane] = acc_o[f][nt][r];
        }
    }
    __syncthreads();

    if (wave == 0) {
#pragma unroll
        for (int f = 0; f < 2; f++) {
            lsum[f] += comb_l[f][lane];
#pragma unroll
            for (int nt = 0; nt < 4; nt++)
#pragma unroll
                for (int r = 0; r < 4; r++)
                    acc_o[f][nt][r] += comb_o[f][nt][r][lane];
        }

#pragma unroll
        for (int f = 0; f < 2; f++) {
            lsum[f] += __shfl_xor(lsum[f], 16, 64);
            lsum[f] += __shfl_xor(lsum[f], 32, 64);
        }
#pragma unroll
        for (int f = 0; f < 2; f++)
#pragma unroll
            for (int r = 0; r < 4; r++) {
                float l_r = __shfl(lsum[f], quad * 4 + r, 64);
                float inv = 1.0f / l_r;
                int q = qb + f * 16 + quad * 4 + r;
                bf16* orow = attn_ws + (size_t)(b_ * SEQ + q) * EMB + h * HD;
#pragma unroll
                for (int nt = 0; nt < 4; nt++)
                    orow[nt * 16 + col] = (bf16)(acc_o[f][nt][r] * inv);
            }
    }
}

// ---------------------------------------------------------------------------
// Kernel 3: output projection  out = attn @ Wo^T   [4096,1024]x[1024,1024]
//  R13: A (attn_ws, bf16) staged via gload_lds; B (Wo, fp32!) reg-staged with
//  in-register conversion — removes the cvt dependency. Same 2-buffer
//  single-barrier pipeline as qkv. 128x128 tile, grid (8,32).
// ---------------------------------------------------------------------------
__global__ __launch_bounds__(256) void oproj_kernel(
    const bf16* __restrict__ attn_ws, const float* __restrict__ Wo,
    float* __restrict__ out)
{
    __shared__ __align__(16) char SM[36864];   // 2 x (As 8KB | Bs 8KB); Es 36KB

    const int t    = threadIdx.x;
    const int lane = t & 63;
    const int wave = t >> 6;
    const int col  = lane & 15;
    const int quad = lane >> 4;

    const int n0 = blockIdx.x * 128;
    const int m0 = blockIdx.y * 128;

    const bf16  *gA[2];
    const float *gB[2];
#pragma unroll
    for (int j = 0; j < 2; j++) {
        int c = t + j * 256;
        gA[j] = attn_ws + (size_t)(m0 + (c >> 2)) * EMB + (c & 3) * 8;
        gB[j] = Wo + (size_t)(n0 + (c >> 2)) * EMB + (c & 3) * 8;
    }

    const int wm = (wave >> 1) * 64;
    const int wn = (wave & 1) * 64;

    f32x4 acc[4][4];
#pragma unroll
    for (int i = 0; i < 4; i++)
#pragma unroll
        for (int j = 0; j < 4; j++) acc[i][j] = (f32x4){0.f, 0.f, 0.f, 0.f};

    float4 rB[2][2];
    auto issue = [&](int kt) {
        const int kc = kt * 32;
#pragma unroll
        for (int j = 0; j < 2; j++) {
            int c = t + j * 256;
            GLOAD_LDS16(gA[j] + kc, (bf16*)(SM + ((kt & 1) * 16384)) + c * 8);
            rB[j][0] = *(const float4*)(gB[j] + kc);
            rB[j][1] = *(const float4*)(gB[j] + kc + 4);
        }
    };
    auto write_buf = [&](int p) {
        bf16* Bs_ = (bf16*)(SM + p * 16384 + 8192);
#pragma unroll
        for (int j = 0; j < 2; j++) {
            int c = t + j * 256;
            *(bf16x8*)(Bs_ + c * 8) = cvt8(rB[j][0], rB[j][1]);
        }
    };
    auto compute = [&](int p) {
        const bf16* As_ = (const bf16*)(SM + p * 16384);
        const bf16* Bs_ = (const bf16*)(SM + p * 16384 + 8192);
        bf16x8 a[4], bb[4];
#pragma unroll
        for (int mt = 0; mt < 4; mt++)
            a[mt] = *(const bf16x8*)(As_ + (wm + mt * 16 + col) * 32 + quad * 8);
#pragma unroll
        for (int nt = 0; nt < 4; nt++)
            bb[nt] = *(const bf16x8*)(Bs_ + (wn + nt * 16 + col) * 32 + quad * 8);
#pragma unroll
        for (int mt = 0; mt < 4; mt++)
#pragma unroll
            for (int nt = 0; nt < 4; nt++)
                acc[mt][nt] = __builtin_amdgcn_mfma_f32_16x16x32_bf16(a[mt], bb[nt], acc[mt][nt], 0, 0, 0);
    };

    issue(0);
    for (int kt = 0; kt < 32; kt++) {
        const int p = kt & 1;
        asm volatile("s_waitcnt vmcnt(0)" ::: "memory");  // A in LDS, B in regs
        write_buf(p);
        __syncthreads();          // vmcnt already 0 -> cheap
        if (kt < 31) issue(kt + 1);
        compute(p);
    }
    __syncthreads();              // LDS reusable for epilogue

    // ---- LDS-transpose epilogue: 2 passes of 64x32 fp32 per wave ----
    float* Os = (float*)(SM + (size_t)wave * 9216);
    const int row = lane >> 3, c8 = lane & 7;
    float* obase = out + (size_t)(m0 + wm) * EMB + n0 + wn;
#pragma unroll
    for (int p = 0; p < 2; p++) {
#pragma unroll
        for (int mt = 0; mt < 4; mt++)
#pragma unroll
            for (int ntl = 0; ntl < 2; ntl++)
#pragma unroll
                for (int r = 0; r < 4; r++)
                    Os[(mt * 16 + quad * 4 + r) * 36 + ntl * 16 + col] = acc[mt][p * 2 + ntl][r];
        // wave-private region: compiler inserts lgkmcnt waits between passes
#pragma unroll
        for (int i = 0; i < 8; i++) {
            float4 vv = *(const float4*)&Os[(i * 8 + row) * 36 + c8 * 4];
            *(float4*)(obase + (size_t)(i * 8 + row) * EMB + p * 32 + c8 * 4) = vv;
        }
    }
}

// ---------------------------------------------------------------------------
// Workspace map (bytes):
//   [ 0, 8M)   q_ws    bf16 [B,H,S,D]  (pre-scaled by 1/32)
//   [ 8,16M)   kf_ws   bf16 fragment-order K
//   [16,24M)   vf_ws   bf16 fragment-order V
//   [24,32M)   attn_ws bf16 [B*S,E]
// ---------------------------------------------------------------------------
extern "C" void kernel_launch(void* const* d_in, const int* in_sizes, int n_in,
                              void* d_out, int out_size, void* d_ws, size_t ws_size,
                              hipStream_t stream) {
    const float* x  = (const float*)d_in[0];
    const float* Wq = (const float*)d_in[1];
    const float* Wk = (const float*)d_in[2];
    const float* Wv = (const float*)d_in[3];
    const float* Wo = (const float*)d_in[4];
    float* out = (float*)d_out;

    char* ws = (char*)d_ws;
    bf16* q_ws    = (bf16*)(ws);
    bf16* kf_ws   = (bf16*)(ws + (8u  << 20));
    bf16* vf_ws   = (bf16*)(ws + (16u << 20));
    bf16* attn_ws = (bf16*)(ws + (24u << 20));

    hipLaunchKernelGGL(qkv_rope_kernel, dim3(24, 32), dim3(256), 0, stream,
                       x, Wq, Wk, Wv, q_ws, kf_ws, vf_ws);
    hipLaunchKernelGGL(attn_kernel, dim3(2048), dim3(128), 0, stream,
                       q_ws, kf_ws, vf_ws, attn_ws);
    hipLaunchKernelGGL(oproj_kernel, dim3(8, 32), dim3(256), 0, stream,
                       attn_ws, Wo, out);
}

// Round 10
// 173.316 us; speedup vs baseline: 1.2605x; 1.2605x over previous
//
#include <hip/hip_runtime.h>
#include <hip/hip_bf16.h>
#include <math.h>

typedef __bf16 bf16;
typedef __bf16 bf16x8 __attribute__((ext_vector_type(8)));
typedef float f32x4 __attribute__((ext_vector_type(4)));

#define SEQ 2048
#define EMB 1024
#define NH  16
#define HD  64
#define NROWS 4096   // B*S

// async global->LDS, 16B per lane (wave-uniform LDS base + lane*16)
#define GLOAD_LDS16(gp, lp)                                             \
    __builtin_amdgcn_global_load_lds(                                   \
        (const __attribute__((address_space(1))) void*)(gp),            \
        (__attribute__((address_space(3))) void*)(lp), 16, 0, 0)

// ---------------------------------------------------------------------------
// Kernel -1: fp32 -> bf16 conversion of all inputs + RoPE table (fused).
//  blocks 0..4095: convert; blocks 4096..4351: cos/sin table.
// ---------------------------------------------------------------------------
__global__ __launch_bounds__(256) void cvt_rope_kernel(
    const float* __restrict__ x,  const float* __restrict__ Wq,
    const float* __restrict__ Wk, const float* __restrict__ Wv,
    const float* __restrict__ Wo,
    bf16* __restrict__ xb, bf16* __restrict__ Wqb, bf16* __restrict__ Wkb,
    bf16* __restrict__ Wvb, bf16* __restrict__ Wob,
    float* __restrict__ ctab, float* __restrict__ stab)
{
    int b = blockIdx.x;
    if (b >= 4096) {
        int t = (b - 4096) * 256 + threadIdx.x;   // 0 .. 65535
        int s = t >> 5;
        int j = t & 31;
        double freq = pow(10000.0, -(double)j / 32.0);
        double ang = (double)s * freq;
        ctab[t] = (float)cos(ang);
        stab[t] = (float)sin(ang);
        return;
    }
    const float* src; bf16* dst; int boff;
    if      (b < 2048) { src = x;  dst = xb;  boff = b;        }
    else if (b < 2560) { src = Wq; dst = Wqb; boff = b - 2048; }
    else if (b < 3072) { src = Wk; dst = Wkb; boff = b - 2560; }
    else if (b < 3584) { src = Wv; dst = Wvb; boff = b - 3072; }
    else               { src = Wo; dst = Wob; boff = b - 3584; }
    size_t off = (size_t)boff * 2048 + (size_t)threadIdx.x * 8;
    float4 f0 = *(const float4*)(src + off);
    float4 f1 = *(const float4*)(src + off + 4);
    bf16x8 v;
    v[0] = (bf16)f0.x; v[1] = (bf16)f0.y; v[2] = (bf16)f0.z; v[3] = (bf16)f0.w;
    v[4] = (bf16)f1.x; v[5] = (bf16)f1.y; v[6] = (bf16)f1.z; v[7] = (bf16)f1.w;
    *(bf16x8*)(dst + off) = v;
}

// ---------------------------------------------------------------------------
// Kernel 1: fused QKV projection (y = x @ W^T) + RoPE epilogue.
//  3-buffer counted-vmcnt pipeline. Q pre-scaled by log2(e)/32 (R14: exp2
//  pre-fold — attn then uses bare v_exp_f32), stored [B,H,S,D].
//  K,V stored in MFMA-fragment order.
// ---------------------------------------------------------------------------
__global__ __launch_bounds__(256) void qkv_rope_kernel(
    const bf16* __restrict__ x,
    const bf16* __restrict__ Wq, const bf16* __restrict__ Wk, const bf16* __restrict__ Wv,
    const float* __restrict__ ctab, const float* __restrict__ stab,
    bf16* __restrict__ q_ws, bf16* __restrict__ kf_ws, bf16* __restrict__ vf_ws)
{
    __shared__ __align__(16) bf16 SMEM[24576];   // 49152 B = 3 x (As 8KB + Bs 8KB)

    const int t    = threadIdx.x;
    const int lane = t & 63;
    const int wave = t >> 6;
    const int col  = lane & 15;
    const int quad = lane >> 4;

    const int nblk = blockIdx.x;              // 0..23
    const int m0   = blockIdx.y * 128;

    const bf16* W; int nloc;
    if (nblk < 8)       { W = Wq; nloc = nblk * 128; }
    else if (nblk < 16) { W = Wk; nloc = (nblk - 8) * 128; }
    else                { W = Wv; nloc = (nblk - 16) * 128; }

    const bf16 *ga[2], *gb[2];
#pragma unroll
    for (int j = 0; j < 2; j++) {
        int c = t + j * 256;
        ga[j] = x + (size_t)(m0 + (c >> 2)) * EMB + (c & 3) * 8;
        gb[j] = W + (size_t)(nloc + (c >> 2)) * EMB + (c & 3) * 8;
    }

    const int wm = (wave >> 1) * 64;
    const int wn = (wave & 1) * 64;

    f32x4 acc[4][4];
#pragma unroll
    for (int i = 0; i < 4; i++)
#pragma unroll
        for (int j = 0; j < 4; j++) acc[i][j] = (f32x4){0.f, 0.f, 0.f, 0.f};

    auto stage = [&](int kt, int b) {
        bf16* As_ = SMEM + b * 8192;
        bf16* Bs_ = As_ + 4096;
        const int kc = kt * 32;
#pragma unroll
        for (int j = 0; j < 2; j++) {
            const int c = t + j * 256;
            GLOAD_LDS16(ga[j] + kc, As_ + c * 8);
            GLOAD_LDS16(gb[j] + kc, Bs_ + c * 8);
        }
    };
    auto compute = [&](int b) {
        bf16* As_ = SMEM + b * 8192;
        bf16* Bs_ = As_ + 4096;
        bf16x8 a[4], bb[4];
#pragma unroll
        for (int mt = 0; mt < 4; mt++)
            a[mt] = *(const bf16x8*)(As_ + (wm + mt * 16 + col) * 32 + quad * 8);
#pragma unroll
        for (int nt = 0; nt < 4; nt++)
            bb[nt] = *(const bf16x8*)(Bs_ + (wn + nt * 16 + col) * 32 + quad * 8);
#pragma unroll
        for (int mt = 0; mt < 4; mt++)
#pragma unroll
            for (int nt = 0; nt < 4; nt++)
                acc[mt][nt] = __builtin_amdgcn_mfma_f32_16x16x32_bf16(a[mt], bb[nt], acc[mt][nt], 0, 0, 0);
    };

    stage(0, 0);            // 4 loads in flight
    stage(1, 1);            // 8 in flight
    int b = 0;
    for (int kt = 0; kt < 31; kt++) {
        // tile kt landed (oldest 4 retired); tile kt+1 still flying
        asm volatile("s_waitcnt vmcnt(4)\n\ts_barrier" ::: "memory");
        if (kt < 30) stage(kt + 2, (kt + 2) % 3);   // overwrite dead buffer (kt-1)
        compute(b);
        b = (b == 2) ? 0 : b + 1;
    }
    asm volatile("s_waitcnt vmcnt(0)\n\ts_barrier" ::: "memory");
    compute(b);             // kt = 31, b = 1
    __syncthreads();        // all LDS reads done -> SMEM reusable for epilogue

    // ---- epilogue: RoPE + LDS transpose -> coalesced stores ----
    bf16* Es = SMEM + wave * 4608;               // 9216 B per wave (Q: 64x72)

    const int n0w  = nblk * 128 + wn;
    const int m0w  = m0 + wm;
    const int bb_  = m0w >> 11;
    const int ss0  = m0w & (SEQ - 1);
    const int h    = (n0w >> 6) & 15;
    const int bh   = bb_ * NH + h;
    const int kind = (n0w < 1024) ? 0 : (n0w < 2048 ? 1 : 2);  // Q/K/V

#pragma unroll
    for (int mt = 0; mt < 4; mt++) {
#pragma unroll
        for (int nt = 0; nt < 4; nt++) {
            const int d  = nt * 16 + col;
            const int jj = d >> 1;
#pragma unroll
            for (int r = 0; r < 4; r++) {
                const int ss_l = mt * 16 + quad * 4 + r;
                float v = acc[mt][nt][r];
                if (kind < 2) {   // uniform per block
                    float partner = __shfl_xor(v, 1, 64);
                    float c  = ctab[(ss0 + ss_l) * 32 + jj];
                    float sn = stab[(ss0 + ss_l) * 32 + jj];
                    float o = ((d & 1) == 0) ? (v * c - partner * sn)
                                             : (partner * sn + v * c);
                    if (kind == 0) {
                        // R14: pre-scale by log2(e)/32 so attn uses raw v_exp_f32
                        Es[ss_l * 72 + d] = (bf16)(o * 0.0450842201f);
                    } else {
                        int eoff = ((ss_l >> 4) * 2 + (d >> 5)) * 512
                                 + ((d >> 3) & 3) * 128 + (ss_l & 15) * 8 + (d & 7);
                        Es[eoff] = (bf16)o;
                    }
                } else {
                    int eoff = ((ss_l >> 5) * 4 + (d >> 4)) * 512
                             + ((ss_l >> 3) & 3) * 128 + (d & 15) * 8 + (ss_l & 7);
                    Es[eoff] = (bf16)v;
                }
            }
        }
    }
    // wave-private region: no barrier needed; compiler inserts lgkmcnt waits.

    const int row = lane >> 3, c8 = lane & 7;
    if (kind == 0) {
        bf16* qbase = q_ws + ((size_t)bh * SEQ + ss0) * HD;
#pragma unroll
        for (int i = 0; i < 8; i++) {
            bf16x8 vv = *(const bf16x8*)&Es[(i * 8 + row) * 72 + c8 * 8];
            *(bf16x8*)(qbase + (size_t)(i * 8 + row) * HD + c8 * 8) = vv;
        }
    } else if (kind == 1) {
        bf16* kbase = kf_ws + ((size_t)bh * 128 + (ss0 >> 4)) * 1024;
#pragma unroll
        for (int i = 0; i < 8; i++) {
            bf16x8 vv = *(const bf16x8*)&Es[i * 512 + lane * 8];
            *(bf16x8*)(kbase + i * 512 + lane * 8) = vv;
        }
    } else {
        bf16* vbase = vf_ws + ((size_t)bh * 64 + (ss0 >> 5)) * 2048;
#pragma unroll
        for (int i = 0; i < 8; i++) {
            bf16x8 vv = *(const bf16x8*)&Es[i * 512 + lane * 8];
            *(bf16x8*)(vbase + i * 512 + lane * 8) = vv;
        }
    }
}

// ---------------------------------------------------------------------------
// Kernel 2: flash attention (causal). Q pre-scaled by log2(e)/32 upstream.
//  Fixed-reference softmax (m=0): split-K partials combine by pure addition.
//  K/V read directly from global in MFMA-fragment order. s_setprio around
//  MFMA clusters. R14: exp via __builtin_amdgcn_exp2f (bare v_exp_f32 —
//  the log2e multiply is folded into Q upstream).
// ---------------------------------------------------------------------------
__global__ __launch_bounds__(128) void attn_kernel(
    const bf16* __restrict__ q_ws, const bf16* __restrict__ kf,
    const bf16* __restrict__ vf, bf16* __restrict__ attn_ws)
{
    __shared__ float comb_o[2][4][4][64];   // [frag][nt][r][lane] from wave1
    __shared__ float comb_l[2][64];

    const int lane = threadIdx.x & 63;
    const int wave = threadIdx.x >> 6;
    const int col  = lane & 15;
    const int quad = lane >> 4;

    const int qt = 63 - (int)(blockIdx.x >> 5);  // longest first, 64 q-tiles of 32
    const int bh = blockIdx.x & 31;              // b*16+h
    const int b_ = bh >> 4;
    const int h  = bh & 15;
    const int qb = qt * 32;
    const int nk = qt + 1;                       // 32-key tiles incl. diagonal

    const bf16* Q  = q_ws + (size_t)bh * SEQ * HD;
    const bf16* Kf = kf + (size_t)bh * 131072;
    const bf16* Vf = vf + (size_t)bh * 131072;

    bf16x8 aq[2][2];
#pragma unroll
    for (int f = 0; f < 2; f++) {
        const bf16* qp = Q + (size_t)(qb + f * 16 + col) * HD + quad * 8;
        aq[f][0] = *(const bf16x8*)(qp);
        aq[f][1] = *(const bf16x8*)(qp + 32);
    }

    f32x4 acc_o[2][4];
#pragma unroll
    for (int f = 0; f < 2; f++)
#pragma unroll
        for (int i = 0; i < 4; i++) acc_o[f][i] = (f32x4){0.f, 0.f, 0.f, 0.f};
    float lsum[2] = {0.f, 0.f};

    int psrc[8];
#pragma unroll
    for (int j = 0; j < 8; j++)
        psrc[j] = ((((quad * 2 + (j >> 2)) & 3) << 4) | col) << 2;

    int s0 = (wave < nk) ? wave : 0;
    bf16x8 Ka[2][2], nKa[2][2];
    {
        const bf16* p = Kf + (size_t)s0 * 2048 + lane * 8;
        Ka[0][0] = *(const bf16x8*)(p);
        Ka[0][1] = *(const bf16x8*)(p + 512);
        Ka[1][0] = *(const bf16x8*)(p + 1024);
        Ka[1][1] = *(const bf16x8*)(p + 1536);
    }

    for (int s = wave; s < nk; s += 2) {
        bf16x8 Vb[4];
        {
            const bf16* p = Vf + (size_t)s * 2048 + lane * 8;
            Vb[0] = *(const bf16x8*)(p);
            Vb[1] = *(const bf16x8*)(p + 512);
            Vb[2] = *(const bf16x8*)(p + 1024);
            Vb[3] = *(const bf16x8*)(p + 1536);
        }

        f32x4 sT[2][2];
        __builtin_amdgcn_s_setprio(1);
#pragma unroll
        for (int g = 0; g < 2; g++)
#pragma unroll
            for (int f = 0; f < 2; f++) {
                f32x4 z = (f32x4){0.f, 0.f, 0.f, 0.f};
                z = __builtin_amdgcn_mfma_f32_16x16x32_bf16(Ka[g][0], aq[f][0], z, 0, 0, 0);
                z = __builtin_amdgcn_mfma_f32_16x16x32_bf16(Ka[g][1], aq[f][1], z, 0, 0, 0);
                sT[g][f] = z;
            }
        __builtin_amdgcn_s_setprio(0);

        {
            int sn = (s + 2 < nk) ? s + 2 : s;
            const bf16* p = Kf + (size_t)sn * 2048 + lane * 8;
            nKa[0][0] = *(const bf16x8*)(p);
            nKa[0][1] = *(const bf16x8*)(p + 512);
            nKa[1][0] = *(const bf16x8*)(p + 1024);
            nKa[1][1] = *(const bf16x8*)(p + 1536);
        }

        float p[2][2][4];
        if (s == nk - 1) {
#pragma unroll
            for (int g = 0; g < 2; g++)
#pragma unroll
                for (int f = 0; f < 2; f++) {
                    const int qg = qb + f * 16 + col;
#pragma unroll
                    for (int r = 0; r < 4; r++) {
                        int key = s * 32 + g * 16 + quad * 4 + r;
                        float e = (key <= qg) ? __builtin_amdgcn_exp2f(sT[g][f][r]) : 0.f;
                        p[g][f][r] = e;
                        lsum[f] += e;
                    }
                }
        } else {
#pragma unroll
            for (int g = 0; g < 2; g++)
#pragma unroll
                for (int f = 0; f < 2; f++)
#pragma unroll
                    for (int r = 0; r < 4; r++) {
                        float e = __builtin_amdgcn_exp2f(sT[g][f][r]);
                        p[g][f][r] = e;
                        lsum[f] += e;
                    }
        }

#pragma unroll
        for (int f = 0; f < 2; f++) {
            unsigned int pk[4];
#pragma unroll
            for (int r = 0; r < 4; r++) {
                unsigned int lo = __builtin_bit_cast(unsigned short, (bf16)p[0][f][r]);
                unsigned int hi = __builtin_bit_cast(unsigned short, (bf16)p[1][f][r]);
                pk[r] = (hi << 16) | lo;
            }
            bf16x8 a_p;
#pragma unroll
            for (int j = 0; j < 8; j++) {
                unsigned int g = (unsigned int)__builtin_amdgcn_ds_bpermute(psrc[j], (int)pk[j & 3]);
                unsigned short bits = (quad < 2) ? (unsigned short)(g & 0xffff)
                                                 : (unsigned short)(g >> 16);
                a_p[j] = __builtin_bit_cast(bf16, bits);
            }
            __builtin_amdgcn_s_setprio(1);
#pragma unroll
            for (int nt = 0; nt < 4; nt++)
                acc_o[f][nt] = __builtin_amdgcn_mfma_f32_16x16x32_bf16(a_p, Vb[nt], acc_o[f][nt], 0, 0, 0);
            __builtin_amdgcn_s_setprio(0);
        }

        Ka[0][0] = nKa[0][0]; Ka[0][1] = nKa[0][1];
        Ka[1][0] = nKa[1][0]; Ka[1][1] = nKa[1][1];
    }

    if (wave == 1) {
#pragma unroll
        for (int f = 0; f < 2; f++) {
            comb_l[f][lane] = lsum[f];
#pragma unroll
            for (int nt = 0; nt < 4; nt++)
#pragma unroll
                for (int r = 0; r < 4; r++)
                    comb_o[f][nt][r][lane] = acc_o[f][nt][r];
        }
    }
    __syncthreads();

    if (wave == 0) {
#pragma unroll
        for (int f = 0; f < 2; f++) {
            lsum[f] += comb_l[f][lane];
#pragma unroll
            for (int nt = 0; nt < 4; nt++)
#pragma unroll
                for (int r = 0; r < 4; r++)
                    acc_o[f][nt][r] += comb_o[f][nt][r][lane];
        }

#pragma unroll
        for (int f = 0; f < 2; f++) {
            lsum[f] += __shfl_xor(lsum[f], 16, 64);
            lsum[f] += __shfl_xor(lsum[f], 32, 64);
        }
#pragma unroll
        for (int f = 0; f < 2; f++)
#pragma unroll
            for (int r = 0; r < 4; r++) {
                float l_r = __shfl(lsum[f], quad * 4 + r, 64);
                float inv = 1.0f / l_r;
                int q = qb + f * 16 + quad * 4 + r;
                bf16* orow = attn_ws + (size_t)(b_ * SEQ + q) * EMB + h * HD;
#pragma unroll
                for (int nt = 0; nt < 4; nt++)
                    orow[nt * 16 + col] = (bf16)(acc_o[f][nt][r] * inv);
            }
    }
}

// ---------------------------------------------------------------------------
// Kernel 3: output projection  out = attn @ Wo^T   [4096,1024]x[1024,1024]
//  128x128 tile, 3-buffer counted-vmcnt loop; LDS-transpose epilogue.
//  Grid MUST be (8,32): n0 = blockIdx.x*128, N=1024. (R15 fix: R14 launched
//  this body at (16,32) -> OOB Wo reads + out writes -> GPU memory fault.)
// ---------------------------------------------------------------------------
__global__ __launch_bounds__(256) void oproj_kernel(
    const bf16* __restrict__ attn_ws, const bf16* __restrict__ Wo,
    float* __restrict__ out)
{
    __shared__ __align__(16) bf16 SMEM[24576];   // 49152 B = 3 x (As 8KB + Bs 8KB)

    const int t    = threadIdx.x;
    const int lane = t & 63;
    const int wave = t >> 6;
    const int col  = lane & 15;
    const int quad = lane >> 4;

    const int n0 = blockIdx.x * 128;
    const int m0 = blockIdx.y * 128;

    const bf16 *ga[2], *gb[2];
#pragma unroll
    for (int j = 0; j < 2; j++) {
        int c = t + j * 256;
        ga[j] = attn_ws + (size_t)(m0 + (c >> 2)) * EMB + (c & 3) * 8;
        gb[j] = Wo + (size_t)(n0 + (c >> 2)) * EMB + (c & 3) * 8;
    }

    const int wm = (wave >> 1) * 64;
    const int wn = (wave & 1) * 64;

    f32x4 acc[4][4];
#pragma unroll
    for (int i = 0; i < 4; i++)
#pragma unroll
        for (int j = 0; j < 4; j++) acc[i][j] = (f32x4){0.f, 0.f, 0.f, 0.f};

    auto stage = [&](int kt, int b) {
        bf16* As_ = SMEM + b * 8192;
        bf16* Bs_ = As_ + 4096;
        const int kc = kt * 32;
#pragma unroll
        for (int j = 0; j < 2; j++) {
            const int c = t + j * 256;
            GLOAD_LDS16(ga[j] + kc, As_ + c * 8);
            GLOAD_LDS16(gb[j] + kc, Bs_ + c * 8);
        }
    };
    auto compute = [&](int b) {
        bf16* As_ = SMEM + b * 8192;
        bf16* Bs_ = As_ + 4096;
        bf16x8 a[4], bb[4];
#pragma unroll
        for (int mt = 0; mt < 4; mt++)
            a[mt] = *(const bf16x8*)(As_ + (wm + mt * 16 + col) * 32 + quad * 8);
#pragma unroll
        for (int nt = 0; nt < 4; nt++)
            bb[nt] = *(const bf16x8*)(Bs_ + (wn + nt * 16 + col) * 32 + quad * 8);
#pragma unroll
        for (int mt = 0; mt < 4; mt++)
#pragma unroll
            for (int nt = 0; nt < 4; nt++)
                acc[mt][nt] = __builtin_amdgcn_mfma_f32_16x16x32_bf16(a[mt], bb[nt], acc[mt][nt], 0, 0, 0);
    };

    stage(0, 0);
    stage(1, 1);
    int b = 0;
    for (int kt = 0; kt < 31; kt++) {
        asm volatile("s_waitcnt vmcnt(4)\n\ts_barrier" ::: "memory");
        if (kt < 30) stage(kt + 2, (kt + 2) % 3);
        compute(b);
        b = (b == 2) ? 0 : b + 1;
    }
    asm volatile("s_waitcnt vmcnt(0)\n\ts_barrier" ::: "memory");
    compute(b);             // kt = 31, b = 1
    __syncthreads();        // LDS reusable for epilogue

    // ---- LDS-transpose epilogue: 2 passes of 64x32 fp32 per wave ----
    float* Os = (float*)SMEM + (size_t)wave * 2304;   // 9216 B per wave
    const int row = lane >> 3, c8 = lane & 7;
    float* obase = out + (size_t)(m0 + wm) * EMB + n0 + wn;
#pragma unroll
    for (int p = 0; p < 2; p++) {
#pragma unroll
        for (int mt = 0; mt < 4; mt++)
#pragma unroll
            for (int ntl = 0; ntl < 2; ntl++)
#pragma unroll
                for (int r = 0; r < 4; r++)
                    Os[(mt * 16 + quad * 4 + r) * 36 + ntl * 16 + col] = acc[mt][p * 2 + ntl][r];
        // wave-private region: compiler inserts lgkmcnt waits between passes
#pragma unroll
        for (int i = 0; i < 8; i++) {
            float4 vv = *(const float4*)&Os[(i * 8 + row) * 36 + c8 * 4];
            *(float4*)(obase + (size_t)(i * 8 + row) * EMB + p * 32 + c8 * 4) = vv;
        }
    }
}

// ---------------------------------------------------------------------------
// Workspace map (bytes):
//   [ 0, 8M)   q_ws   bf16 [B,H,S,D]  (pre-scaled by log2(e)/32)
//   [ 8,16M)   kf_ws  bf16 fragment-order K
//   [16,24M)   vf_ws  bf16 fragment-order V
//   [24,32M)   xb     bf16 [B*S,E]     -- dead after qkv; reused as attn_ws
//   [32,34M)   Wqb    bf16 [E,E]
//   [34,36M)   Wkb
//   [36,38M)   Wvb
//   [38,40M)   Wob
//   [40,40.5M) ctab/stab fp32 [S,32] each
// ---------------------------------------------------------------------------
extern "C" void kernel_launch(void* const* d_in, const int* in_sizes, int n_in,
                              void* d_out, int out_size, void* d_ws, size_t ws_size,
                              hipStream_t stream) {
    const float* x  = (const float*)d_in[0];
    const float* Wq = (const float*)d_in[1];
    const float* Wk = (const float*)d_in[2];
    const float* Wv = (const float*)d_in[3];
    const float* Wo = (const float*)d_in[4];
    float* out = (float*)d_out;

    char* ws = (char*)d_ws;
    bf16* q_ws    = (bf16*)(ws);
    bf16* kf_ws   = (bf16*)(ws + (8u  << 20));
    bf16* vf_ws   = (bf16*)(ws + (16u << 20));
    bf16* xb      = (bf16*)(ws + (24u << 20));
    bf16* attn_ws = (bf16*)(ws + (24u << 20));   // aliases xb (dead by then)
    bf16* Wqb     = (bf16*)(ws + (32u << 20));
    bf16* Wkb     = (bf16*)(ws + (34u << 20));
    bf16* Wvb     = (bf16*)(ws + (36u << 20));
    bf16* Wob     = (bf16*)(ws + (38u << 20));
    float* ctab   = (float*)(ws + (40u << 20));
    float* stab   = ctab + SEQ * 32;

    hipLaunchKernelGGL(cvt_rope_kernel, dim3(4352), dim3(256), 0, stream,
                       x, Wq, Wk, Wv, Wo, xb, Wqb, Wkb, Wvb, Wob, ctab, stab);
    hipLaunchKernelGGL(qkv_rope_kernel, dim3(24, 32), dim3(256), 0, stream,
                       xb, Wqb, Wkb, Wvb, ctab, stab, q_ws, kf_ws, vf_ws);
    hipLaunchKernelGGL(attn_kernel, dim3(2048), dim3(128), 0, stream,
                       q_ws, kf_ws, vf_ws, attn_ws);
    hipLaunchKernelGGL(oproj_kernel, dim3(8, 32), dim3(256), 0, stream,
                       attn_ws, Wob, out);
}

// Round 16
// 170.115 us; speedup vs baseline: 1.2843x; 1.0188x over previous
//
#include <hip/hip_runtime.h>
#include <hip/hip_bf16.h>
#include <math.h>

typedef __bf16 bf16;
typedef __bf16 bf16x8 __attribute__((ext_vector_type(8)));
typedef float f32x4 __attribute__((ext_vector_type(4)));
typedef unsigned int u32x2 __attribute__((ext_vector_type(2)));

#define SEQ 2048
#define EMB 1024
#define NH  16
#define HD  64
#define NROWS 4096   // B*S

// async global->LDS, 16B per lane (wave-uniform LDS base + lane*16)
#define GLOAD_LDS16(gp, lp)                                             \
    __builtin_amdgcn_global_load_lds(                                   \
        (const __attribute__((address_space(1))) void*)(gp),            \
        (__attribute__((address_space(3))) void*)(lp), 16, 0, 0)

// pack two fp32 into one word of two bf16 (lo = a, hi = b)
__device__ __forceinline__ unsigned int pkpair(float a, float b) {
    unsigned int lo = __builtin_bit_cast(unsigned short, (bf16)a);
    unsigned int hi = __builtin_bit_cast(unsigned short, (bf16)b);
    return (hi << 16) | lo;
}

// ---------------------------------------------------------------------------
// Kernel -1: fp32 -> bf16 conversion of all inputs + RoPE table (fused).
//  blocks 0..4095: convert; blocks 4096..4351: cos/sin table.
// ---------------------------------------------------------------------------
__global__ __launch_bounds__(256) void cvt_rope_kernel(
    const float* __restrict__ x,  const float* __restrict__ Wq,
    const float* __restrict__ Wk, const float* __restrict__ Wv,
    const float* __restrict__ Wo,
    bf16* __restrict__ xb, bf16* __restrict__ Wqb, bf16* __restrict__ Wkb,
    bf16* __restrict__ Wvb, bf16* __restrict__ Wob,
    float* __restrict__ ctab, float* __restrict__ stab)
{
    int b = blockIdx.x;
    if (b >= 4096) {
        int t = (b - 4096) * 256 + threadIdx.x;   // 0 .. 65535
        int s = t >> 5;
        int j = t & 31;
        double freq = pow(10000.0, -(double)j / 32.0);
        double ang = (double)s * freq;
        ctab[t] = (float)cos(ang);
        stab[t] = (float)sin(ang);
        return;
    }
    const float* src; bf16* dst; int boff;
    if      (b < 2048) { src = x;  dst = xb;  boff = b;        }
    else if (b < 2560) { src = Wq; dst = Wqb; boff = b - 2048; }
    else if (b < 3072) { src = Wk; dst = Wkb; boff = b - 2560; }
    else if (b < 3584) { src = Wv; dst = Wvb; boff = b - 3072; }
    else               { src = Wo; dst = Wob; boff = b - 3584; }
    size_t off = (size_t)boff * 2048 + (size_t)threadIdx.x * 8;
    float4 f0 = *(const float4*)(src + off);
    float4 f1 = *(const float4*)(src + off + 4);
    bf16x8 v;
    v[0] = (bf16)f0.x; v[1] = (bf16)f0.y; v[2] = (bf16)f0.z; v[3] = (bf16)f0.w;
    v[4] = (bf16)f1.x; v[5] = (bf16)f1.y; v[6] = (bf16)f1.z; v[7] = (bf16)f1.w;
    *(bf16x8*)(dst + off) = v;
}

// ---------------------------------------------------------------------------
// Kernel 1: fused QKV projection (y = x @ W^T) + RoPE epilogue.
//  3-buffer counted-vmcnt pipeline. Q pre-scaled by log2(e)/32 (exp2
//  pre-fold — attn uses bare v_exp_f32), stored [B,H,S,D].
//  K,V stored in MFMA-fragment order.
// ---------------------------------------------------------------------------
__global__ __launch_bounds__(256) void qkv_rope_kernel(
    const bf16* __restrict__ x,
    const bf16* __restrict__ Wq, const bf16* __restrict__ Wk, const bf16* __restrict__ Wv,
    const float* __restrict__ ctab, const float* __restrict__ stab,
    bf16* __restrict__ q_ws, bf16* __restrict__ kf_ws, bf16* __restrict__ vf_ws)
{
    __shared__ __align__(16) bf16 SMEM[24576];   // 49152 B = 3 x (As 8KB + Bs 8KB)

    const int t    = threadIdx.x;
    const int lane = t & 63;
    const int wave = t >> 6;
    const int col  = lane & 15;
    const int quad = lane >> 4;

    const int nblk = blockIdx.x;              // 0..23
    const int m0   = blockIdx.y * 128;

    const bf16* W; int nloc;
    if (nblk < 8)       { W = Wq; nloc = nblk * 128; }
    else if (nblk < 16) { W = Wk; nloc = (nblk - 8) * 128; }
    else                { W = Wv; nloc = (nblk - 16) * 128; }

    const bf16 *ga[2], *gb[2];
#pragma unroll
    for (int j = 0; j < 2; j++) {
        int c = t + j * 256;
        ga[j] = x + (size_t)(m0 + (c >> 2)) * EMB + (c & 3) * 8;
        gb[j] = W + (size_t)(nloc + (c >> 2)) * EMB + (c & 3) * 8;
    }

    const int wm = (wave >> 1) * 64;
    const int wn = (wave & 1) * 64;

    f32x4 acc[4][4];
#pragma unroll
    for (int i = 0; i < 4; i++)
#pragma unroll
        for (int j = 0; j < 4; j++) acc[i][j] = (f32x4){0.f, 0.f, 0.f, 0.f};

    auto stage = [&](int kt, int b) {
        bf16* As_ = SMEM + b * 8192;
        bf16* Bs_ = As_ + 4096;
        const int kc = kt * 32;
#pragma unroll
        for (int j = 0; j < 2; j++) {
            const int c = t + j * 256;
            GLOAD_LDS16(ga[j] + kc, As_ + c * 8);
            GLOAD_LDS16(gb[j] + kc, Bs_ + c * 8);
        }
    };
    auto compute = [&](int b) {
        bf16* As_ = SMEM + b * 8192;
        bf16* Bs_ = As_ + 4096;
        bf16x8 a[4], bb[4];
#pragma unroll
        for (int mt = 0; mt < 4; mt++)
            a[mt] = *(const bf16x8*)(As_ + (wm + mt * 16 + col) * 32 + quad * 8);
#pragma unroll
        for (int nt = 0; nt < 4; nt++)
            bb[nt] = *(const bf16x8*)(Bs_ + (wn + nt * 16 + col) * 32 + quad * 8);
#pragma unroll
        for (int mt = 0; mt < 4; mt++)
#pragma unroll
            for (int nt = 0; nt < 4; nt++)
                acc[mt][nt] = __builtin_amdgcn_mfma_f32_16x16x32_bf16(a[mt], bb[nt], acc[mt][nt], 0, 0, 0);
    };

    stage(0, 0);            // 4 loads in flight
    stage(1, 1);            // 8 in flight
    int b = 0;
    for (int kt = 0; kt < 31; kt++) {
        // tile kt landed (oldest 4 retired); tile kt+1 still flying
        asm volatile("s_waitcnt vmcnt(4)\n\ts_barrier" ::: "memory");
        if (kt < 30) stage(kt + 2, (kt + 2) % 3);   // overwrite dead buffer (kt-1)
        compute(b);
        b = (b == 2) ? 0 : b + 1;
    }
    asm volatile("s_waitcnt vmcnt(0)\n\ts_barrier" ::: "memory");
    compute(b);             // kt = 31, b = 1
    __syncthreads();        // all LDS reads done -> SMEM reusable for epilogue

    // ---- epilogue: RoPE + LDS transpose -> coalesced stores ----
    bf16* Es = SMEM + wave * 4608;               // 9216 B per wave (Q: 64x72)

    const int n0w  = nblk * 128 + wn;
    const int m0w  = m0 + wm;
    const int bb_  = m0w >> 11;
    const int ss0  = m0w & (SEQ - 1);
    const int h    = (n0w >> 6) & 15;
    const int bh   = bb_ * NH + h;
    const int kind = (n0w < 1024) ? 0 : (n0w < 2048 ? 1 : 2);  // Q/K/V

#pragma unroll
    for (int mt = 0; mt < 4; mt++) {
#pragma unroll
        for (int nt = 0; nt < 4; nt++) {
            const int d  = nt * 16 + col;
            const int jj = d >> 1;
#pragma unroll
            for (int r = 0; r < 4; r++) {
                const int ss_l = mt * 16 + quad * 4 + r;
                float v = acc[mt][nt][r];
                if (kind < 2) {   // uniform per block
                    float partner = __shfl_xor(v, 1, 64);
                    float c  = ctab[(ss0 + ss_l) * 32 + jj];
                    float sn = stab[(ss0 + ss_l) * 32 + jj];
                    float o = ((d & 1) == 0) ? (v * c - partner * sn)
                                             : (partner * sn + v * c);
                    if (kind == 0) {
                        // pre-scale by log2(e)/32 so attn uses raw v_exp_f32
                        Es[ss_l * 72 + d] = (bf16)(o * 0.0450842201f);
                    } else {
                        int eoff = ((ss_l >> 4) * 2 + (d >> 5)) * 512
                                 + ((d >> 3) & 3) * 128 + (ss_l & 15) * 8 + (d & 7);
                        Es[eoff] = (bf16)o;
                    }
                } else {
                    int eoff = ((ss_l >> 5) * 4 + (d >> 4)) * 512
                             + ((ss_l >> 3) & 3) * 128 + (d & 15) * 8 + (ss_l & 7);
                    Es[eoff] = (bf16)v;
                }
            }
        }
    }
    // wave-private region: no barrier needed; compiler inserts lgkmcnt waits.

    const int row = lane >> 3, c8 = lane & 7;
    if (kind == 0) {
        bf16* qbase = q_ws + ((size_t)bh * SEQ + ss0) * HD;
#pragma unroll
        for (int i = 0; i < 8; i++) {
            bf16x8 vv = *(const bf16x8*)&Es[(i * 8 + row) * 72 + c8 * 8];
            *(bf16x8*)(qbase + (size_t)(i * 8 + row) * HD + c8 * 8) = vv;
        }
    } else if (kind == 1) {
        bf16* kbase = kf_ws + ((size_t)bh * 128 + (ss0 >> 4)) * 1024;
#pragma unroll
        for (int i = 0; i < 8; i++) {
            bf16x8 vv = *(const bf16x8*)&Es[i * 512 + lane * 8];
            *(bf16x8*)(kbase + i * 512 + lane * 8) = vv;
        }
    } else {
        bf16* vbase = vf_ws + ((size_t)bh * 64 + (ss0 >> 5)) * 2048;
#pragma unroll
        for (int i = 0; i < 8; i++) {
            bf16x8 vv = *(const bf16x8*)&Es[i * 512 + lane * 8];
            *(bf16x8*)(vbase + i * 512 + lane * 8) = vv;
        }
    }
}

// ---------------------------------------------------------------------------
// Kernel 2: flash attention (causal). Q pre-scaled by log2(e)/32 upstream.
//  Fixed-reference softmax (m=0): split-K partials combine by pure addition.
//  K/V read directly from global in MFMA-fragment order. s_setprio around
//  MFMA clusters. exp via __builtin_amdgcn_exp2f.
//  R16: P->PV routing via LDS round-trip instead of 16 ds_bpermute + 16
//  selects. PV's A-operand needs lane(col,quad) to hold P[key=quad*8+j][q=col]
//  (8 consecutive keys of one row) = one ds_read_b128 from P_lds[q][key].
//  Producer lane writes its key-pairs as 2x ds_write_b64 of packed bf16.
//  Per key-step: 8 packs + 4 writes + 2 reads vs 8 packs + 16 bpermute +
//  16 selects. Values bit-identical (same bf16, different routing).
//  Key stride padded to 40 elem (80 B row): b128-aligned, bank-spread.
// ---------------------------------------------------------------------------
__global__ __launch_bounds__(128) void attn_kernel(
    const bf16* __restrict__ q_ws, const bf16* __restrict__ kf,
    const bf16* __restrict__ vf, bf16* __restrict__ attn_ws)
{
    __shared__ float comb_o[2][4][4][64];   // [frag][nt][r][lane] from wave1
    __shared__ float comb_l[2][64];
    __shared__ __align__(16) bf16 pex[2 * 2 * 640];  // [wave][f][16 q][40 keys]

    const int lane = threadIdx.x & 63;
    const int wave = threadIdx.x >> 6;
    const int col  = lane & 15;
    const int quad = lane >> 4;

    const int qt = 63 - (int)(blockIdx.x >> 5);  // longest first, 64 q-tiles of 32
    const int bh = blockIdx.x & 31;              // b*16+h
    const int b_ = bh >> 4;
    const int h  = bh & 15;
    const int qb = qt * 32;
    const int nk = qt + 1;                       // 32-key tiles incl. diagonal

    const bf16* Q  = q_ws + (size_t)bh * SEQ * HD;
    const bf16* Kf = kf + (size_t)bh * 131072;
    const bf16* Vf = vf + (size_t)bh * 131072;

    // per-wave/per-f exchange regions; addresses constant per lane
    bf16* Ep0 = pex + wave * 1280;
    bf16* Ep1 = Ep0 + 640;
    const int wr0 = col * 40 + quad * 4;         // keys quad*4+r   (g=0)
    const int wr1 = wr0 + 16;                    // keys 16+quad*4+r (g=1)
    const int rd  = col * 40 + quad * 8;         // keys quad*8..+7

    bf16x8 aq[2][2];
#pragma unroll
    for (int f = 0; f < 2; f++) {
        const bf16* qp = Q + (size_t)(qb + f * 16 + col) * HD + quad * 8;
        aq[f][0] = *(const bf16x8*)(qp);
        aq[f][1] = *(const bf16x8*)(qp + 32);
    }

    f32x4 acc_o[2][4];
#pragma unroll
    for (int f = 0; f < 2; f++)
#pragma unroll
        for (int i = 0; i < 4; i++) acc_o[f][i] = (f32x4){0.f, 0.f, 0.f, 0.f};
    float lsum[2] = {0.f, 0.f};

    int s0 = (wave < nk) ? wave : 0;
    bf16x8 Ka[2][2], nKa[2][2];
    {
        const bf16* p = Kf + (size_t)s0 * 2048 + lane * 8;
        Ka[0][0] = *(const bf16x8*)(p);
        Ka[0][1] = *(const bf16x8*)(p + 512);
        Ka[1][0] = *(const bf16x8*)(p + 1024);
        Ka[1][1] = *(const bf16x8*)(p + 1536);
    }

    for (int s = wave; s < nk; s += 2) {
        bf16x8 Vb[4];
        {
            const bf16* p = Vf + (size_t)s * 2048 + lane * 8;
            Vb[0] = *(const bf16x8*)(p);
            Vb[1] = *(const bf16x8*)(p + 512);
            Vb[2] = *(const bf16x8*)(p + 1024);
            Vb[3] = *(const bf16x8*)(p + 1536);
        }

        f32x4 sT[2][2];
        __builtin_amdgcn_s_setprio(1);
#pragma unroll
        for (int g = 0; g < 2; g++)
#pragma unroll
            for (int f = 0; f < 2; f++) {
                f32x4 z = (f32x4){0.f, 0.f, 0.f, 0.f};
                z = __builtin_amdgcn_mfma_f32_16x16x32_bf16(Ka[g][0], aq[f][0], z, 0, 0, 0);
                z = __builtin_amdgcn_mfma_f32_16x16x32_bf16(Ka[g][1], aq[f][1], z, 0, 0, 0);
                sT[g][f] = z;
            }
        __builtin_amdgcn_s_setprio(0);

        {
            int sn = (s + 2 < nk) ? s + 2 : s;
            const bf16* p = Kf + (size_t)sn * 2048 + lane * 8;
            nKa[0][0] = *(const bf16x8*)(p);
            nKa[0][1] = *(const bf16x8*)(p + 512);
            nKa[1][0] = *(const bf16x8*)(p + 1024);
            nKa[1][1] = *(const bf16x8*)(p + 1536);
        }

        float p[2][2][4];
        if (s == nk - 1) {
#pragma unroll
            for (int g = 0; g < 2; g++)
#pragma unroll
                for (int f = 0; f < 2; f++) {
                    const int qg = qb + f * 16 + col;
#pragma unroll
                    for (int r = 0; r < 4; r++) {
                        int key = s * 32 + g * 16 + quad * 4 + r;
                        float e = (key <= qg) ? __builtin_amdgcn_exp2f(sT[g][f][r]) : 0.f;
                        p[g][f][r] = e;
                        lsum[f] += e;
                    }
                }
        } else {
#pragma unroll
            for (int g = 0; g < 2; g++)
#pragma unroll
                for (int f = 0; f < 2; f++)
#pragma unroll
                    for (int r = 0; r < 4; r++) {
                        float e = __builtin_amdgcn_exp2f(sT[g][f][r]);
                        p[g][f][r] = e;
                        lsum[f] += e;
                    }
        }

        // ---- P exchange via LDS: write key-pairs, read A-fragments ----
#pragma unroll
        for (int f = 0; f < 2; f++) {
            bf16* Ep = (f == 0) ? Ep0 : Ep1;
            unsigned int w0 = pkpair(p[0][f][0], p[0][f][1]);
            unsigned int w1 = pkpair(p[0][f][2], p[0][f][3]);
            unsigned int w2 = pkpair(p[1][f][0], p[1][f][1]);
            unsigned int w3 = pkpair(p[1][f][2], p[1][f][3]);
            *(u32x2*)(Ep + wr0) = (u32x2){w0, w1};
            *(u32x2*)(Ep + wr1) = (u32x2){w2, w3};
        }
        // wave-private region: compiler inserts lgkmcnt waits for RAW dep
        bf16x8 ap0 = *(const bf16x8*)(Ep0 + rd);
        bf16x8 ap1 = *(const bf16x8*)(Ep1 + rd);

        __builtin_amdgcn_s_setprio(1);
#pragma unroll
        for (int nt = 0; nt < 4; nt++)
            acc_o[0][nt] = __builtin_amdgcn_mfma_f32_16x16x32_bf16(ap0, Vb[nt], acc_o[0][nt], 0, 0, 0);
#pragma unroll
        for (int nt = 0; nt < 4; nt++)
            acc_o[1][nt] = __builtin_amdgcn_mfma_f32_16x16x32_bf16(ap1, Vb[nt], acc_o[1][nt], 0, 0, 0);
        __builtin_amdgcn_s_setprio(0);

        Ka[0][0] = nKa[0][0]; Ka[0][1] = nKa[0][1];
        Ka[1][0] = nKa[1][0]; Ka[1][1] = nKa[1][1];
    }

    if (wave == 1) {
#pragma unroll
        for (int f = 0; f < 2; f++) {
            comb_l[f][lane] = lsum[f];
#pragma unroll
            for (int nt = 0; nt < 4; nt++)
#pragma unroll
                for (int r = 0; r < 4; r++)
                    comb_o[f][nt][r][lane] = acc_o[f][nt][r];
        }
    }
    __syncthreads();

    if (wave == 0) {
#pragma unroll
        for (int f = 0; f < 2; f++) {
            lsum[f] += comb_l[f][lane];
#pragma unroll
            for (int nt = 0; nt < 4; nt++)
#pragma unroll
                for (int r = 0; r < 4; r++)
                    acc_o[f][nt][r] += comb_o[f][nt][r][lane];
        }

#pragma unroll
        for (int f = 0; f < 2; f++) {
            lsum[f] += __shfl_xor(lsum[f], 16, 64);
            lsum[f] += __shfl_xor(lsum[f], 32, 64);
        }
#pragma unroll
        for (int f = 0; f < 2; f++)
#pragma unroll
            for (int r = 0; r < 4; r++) {
                float l_r = __shfl(lsum[f], quad * 4 + r, 64);
                float inv = 1.0f / l_r;
                int q = qb + f * 16 + quad * 4 + r;
                bf16* orow = attn_ws + (size_t)(b_ * SEQ + q) * EMB + h * HD;
#pragma unroll
                for (int nt = 0; nt < 4; nt++)
                    orow[nt * 16 + col] = (bf16)(acc_o[f][nt][r] * inv);
            }
    }
}

// ---------------------------------------------------------------------------
// Kernel 3: output projection  out = attn @ Wo^T   [4096,1024]x[1024,1024]
//  128x128 tile, 3-buffer counted-vmcnt loop; LDS-transpose epilogue.
//  Grid MUST be (8,32): n0 = blockIdx.x*128, N=1024.
// ---------------------------------------------------------------------------
__global__ __launch_bounds__(256) void oproj_kernel(
    const bf16* __restrict__ attn_ws, const bf16* __restrict__ Wo,
    float* __restrict__ out)
{
    __shared__ __align__(16) bf16 SMEM[24576];   // 49152 B = 3 x (As 8KB + Bs 8KB)

    const int t    = threadIdx.x;
    const int lane = t & 63;
    const int wave = t >> 6;
    const int col  = lane & 15;
    const int quad = lane >> 4;

    const int n0 = blockIdx.x * 128;
    const int m0 = blockIdx.y * 128;

    const bf16 *ga[2], *gb[2];
#pragma unroll
    for (int j = 0; j < 2; j++) {
        int c = t + j * 256;
        ga[j] = attn_ws + (size_t)(m0 + (c >> 2)) * EMB + (c & 3) * 8;
        gb[j] = Wo + (size_t)(n0 + (c >> 2)) * EMB + (c & 3) * 8;
    }

    const int wm = (wave >> 1) * 64;
    const int wn = (wave & 1) * 64;

    f32x4 acc[4][4];
#pragma unroll
    for (int i = 0; i < 4; i++)
#pragma unroll
        for (int j = 0; j < 4; j++) acc[i][j] = (f32x4){0.f, 0.f, 0.f, 0.f};

    auto stage = [&](int kt, int b) {
        bf16* As_ = SMEM + b * 8192;
        bf16* Bs_ = As_ + 4096;
        const int kc = kt * 32;
#pragma unroll
        for (int j = 0; j < 2; j++) {
            const int c = t + j * 256;
            GLOAD_LDS16(ga[j] + kc, As_ + c * 8);
            GLOAD_LDS16(gb[j] + kc, Bs_ + c * 8);
        }
    };
    auto compute = [&](int b) {
        bf16* As_ = SMEM + b * 8192;
        bf16* Bs_ = As_ + 4096;
        bf16x8 a[4], bb[4];
#pragma unroll
        for (int mt = 0; mt < 4; mt++)
            a[mt] = *(const bf16x8*)(As_ + (wm + mt * 16 + col) * 32 + quad * 8);
#pragma unroll
        for (int nt = 0; nt < 4; nt++)
            bb[nt] = *(const bf16x8*)(Bs_ + (wn + nt * 16 + col) * 32 + quad * 8);
#pragma unroll
        for (int mt = 0; mt < 4; mt++)
#pragma unroll
            for (int nt = 0; nt < 4; nt++)
                acc[mt][nt] = __builtin_amdgcn_mfma_f32_16x16x32_bf16(a[mt], bb[nt], acc[mt][nt], 0, 0, 0);
    };

    stage(0, 0);
    stage(1, 1);
    int b = 0;
    for (int kt = 0; kt < 31; kt++) {
        asm volatile("s_waitcnt vmcnt(4)\n\ts_barrier" ::: "memory");
        if (kt < 30) stage(kt + 2, (kt + 2) % 3);
        compute(b);
        b = (b == 2) ? 0 : b + 1;
    }
    asm volatile("s_waitcnt vmcnt(0)\n\ts_barrier" ::: "memory");
    compute(b);             // kt = 31, b = 1
    __syncthreads();        // LDS reusable for epilogue

    // ---- LDS-transpose epilogue: 2 passes of 64x32 fp32 per wave ----
    float* Os = (float*)SMEM + (size_t)wave * 2304;   // 9216 B per wave
    const int row = lane >> 3, c8 = lane & 7;
    float* obase = out + (size_t)(m0 + wm) * EMB + n0 + wn;
#pragma unroll
    for (int p = 0; p < 2; p++) {
#pragma unroll
        for (int mt = 0; mt < 4; mt++)
#pragma unroll
            for (int ntl = 0; ntl < 2; ntl++)
#pragma unroll
                for (int r = 0; r < 4; r++)
                    Os[(mt * 16 + quad * 4 + r) * 36 + ntl * 16 + col] = acc[mt][p * 2 + ntl][r];
        // wave-private region: compiler inserts lgkmcnt waits between passes
#pragma unroll
        for (int i = 0; i < 8; i++) {
            float4 vv = *(const float4*)&Os[(i * 8 + row) * 36 + c8 * 4];
            *(float4*)(obase + (size_t)(i * 8 + row) * EMB + p * 32 + c8 * 4) = vv;
        }
    }
}

// ---------------------------------------------------------------------------
// Workspace map (bytes):
//   [ 0, 8M)   q_ws   bf16 [B,H,S,D]  (pre-scaled by log2(e)/32)
//   [ 8,16M)   kf_ws  bf16 fragment-order K
//   [16,24M)   vf_ws  bf16 fragment-order V
//   [24,32M)   xb     bf16 [B*S,E]     -- dead after qkv; reused as attn_ws
//   [32,34M)   Wqb    bf16 [E,E]
//   [34,36M)   Wkb
//   [36,38M)   Wvb
//   [38,40M)   Wob
//   [40,40.5M) ctab/stab fp32 [S,32] each
// ---------------------------------------------------------------------------
extern "C" void kernel_launch(void* const* d_in, const int* in_sizes, int n_in,
                              void* d_out, int out_size, void* d_ws, size_t ws_size,
                              hipStream_t stream) {
    const float* x  = (const float*)d_in[0];
    const float* Wq = (const float*)d_in[1];
    const float* Wk = (const float*)d_in[2];
    const float* Wv = (const float*)d_in[3];
    const float* Wo = (const float*)d_in[4];
    float* out = (float*)d_out;

    char* ws = (char*)d_ws;
    bf16* q_ws    = (bf16*)(ws);
    bf16* kf_ws   = (bf16*)(ws + (8u  << 20));
    bf16* vf_ws   = (bf16*)(ws + (16u << 20));
    bf16* xb      = (bf16*)(ws + (24u << 20));
    bf16* attn_ws = (bf16*)(ws + (24u << 20));   // aliases xb (dead by then)
    bf16* Wqb     = (bf16*)(ws + (32u << 20));
    bf16* Wkb     = (bf16*)(ws + (34u << 20));
    bf16* Wvb     = (bf16*)(ws + (36u << 20));
    bf16* Wob     = (bf16*)(ws + (38u << 20));
    float* ctab   = (float*)(ws + (40u << 20));
    float* stab   = ctab + SEQ * 32;

    hipLaunchKernelGGL(cvt_rope_kernel, dim3(4352), dim3(256), 0, stream,
                       x, Wq, Wk, Wv, Wo, xb, Wqb, Wkb, Wvb, Wob, ctab, stab);
    hipLaunchKernelGGL(qkv_rope_kernel, dim3(24, 32), dim3(256), 0, stream,
                       xb, Wqb, Wkb, Wvb, ctab, stab, q_ws, kf_ws, vf_ws);
    hipLaunchKernelGGL(attn_kernel, dim3(2048), dim3(128), 0, stream,
                       q_ws, kf_ws, vf_ws, attn_ws);
    hipLaunchKernelGGL(oproj_kernel, dim3(8, 32), dim3(256), 0, stream,
                       attn_ws, Wob, out);
}